// Round 13
// baseline (107.913 us; speedup 1.0000x reference)
//
#include <hip/hip_runtime.h>
#include <math.h>

// B=16, O=24, V=2, P0=32, P1=64, P2=64, R=3, C=16, UI=1, BI=2
// NUM_IN=288, P=552 (p=a*23+j, bb=j+(j>=a), aadj=a-(a>bb))
// conj(b,p,r,c) = U1(b,a)·U2(b,bb)·T3(b,a,j)·T4(b,bb,aadj)
//   U1: nullary(i 0..32)+unary[a] (i 32..96); U2: unary row seg (i 96..160)
//   T3: binary row × seg3 coeffs (i 160..224); T4: same row × seg4 (i 224..288)
// out: [nullary_out(16) | unary_out(16*24) | binary_out(16*24*23)]

#define XJST 68

__device__ __forceinline__ float sigm(float x) { return 1.0f / (1.0f + expf(-x)); }

// softmax(ak[r][c][i][0..2]/T) -> (d=s0-s1, e=s1+s2); term = fma(x,d,e)
__device__ __forceinline__ float2 dke_of(const float* __restrict__ akp, float invT) {
    float a0 = akp[0] * invT, a1 = akp[1] * invT, a2 = akp[2] * invT;
    float mx = fmaxf(a0, fmaxf(a1, a2));
    float e0 = expf(a0 - mx), e1 = expf(a1 - mx), e2 = expf(a2 - mx);
    float inv = 1.0f / (e0 + e1 + e2);
    float s0 = e0 * inv, s1 = e1 * inv, s2 = e2 * inv;
    return make_float2(s0 - s1, s1 + s2);
}

// ---------------- Kernel 1: per-(b,a) factors: T3/T4 for own 23 rows, U1, U2 ----------------
// grid: 16*24 = 384 blocks. block: 256 threads = pj(16) x c(16).
__global__ __launch_bounds__(256) void fused_kernel(const float* __restrict__ nullary,
                                                    const float* __restrict__ unary,
                                                    const float* __restrict__ binary,
                                                    const float* __restrict__ ak,
                                                    const float* __restrict__ temp,
                                                    float* __restrict__ t3,
                                                    float* __restrict__ t4,
                                                    float* __restrict__ U1,
                                                    float* __restrict__ U2) {
    __shared__ float ck[128 * 16 * 6];  // 49.2 KB: seg3 (i 0..64) | seg4 (i 64..128)
    __shared__ float xj[24 * XJST];     // 6.5 KB: own binary rows (23 + pad)
    __shared__ float xu[64];            // unary[a] row
    __shared__ float xn[32];            // nullary row

    const int tid = threadIdx.x;
    const int ba = blockIdx.x;
    const int b = ba / 24;
    const int a = ba % 24;
    const float invT = 1.0f / temp[0];

    // ---- stage x rows ----
    for (int idx = tid; idx < 24 * 16; idx += 256) {
        int j = idx >> 4, q = idx & 15;
        int je = j < 23 ? j : 22;
        float4 v = *(const float4*)(binary + (((size_t)b * 24 + a) * 23 + je) * 64 + q * 4);
        *(float4*)&xj[j * XJST + q * 4] = v;
    }
    if (tid >= 384 && tid < 384 + 16) {
        int q = tid - 384;
        *(float4*)&xu[q * 4] = *(const float4*)(unary + ((size_t)b * 24 + a) * 64 + q * 4);
    }
    if (tid >= 416 && tid < 416 + 8) {
        int q = tid - 416;
        *(float4*)&xn[q * 4] = *(const float4*)(nullary + b * 32 + q * 4);
    }
    // ---- seg3/seg4 coefficients inline (i34 0..128 -> global i 160..288) ----
    for (int idx = tid; idx < 128 * 16; idx += 256) {
        int i34 = idx >> 4, c = idx & 15;
        float* q = &ck[(size_t)idx * 6];
#pragma unroll
        for (int r = 0; r < 3; ++r) {
            float2 de = dke_of(ak + (((size_t)(r * 16 + c) * 288) + 160 + i34) * 3, invT);
            q[2 * r] = de.x; q[2 * r + 1] = de.y;
        }
    }
    __syncthreads();

    // ---- T-compute: thread (pj,c) -> T3,T4 for j1=pj, j2=pj+16 (register-resident) ----
    const int pj = tid >> 4;
    const int c  = tid & 15;
    const int j1 = pj;
    const int j2 = pj + 16;
    const int j2e = j2 < 23 ? j2 : 22;

    float t3a[2][3], t4a[2][3];
#pragma unroll
    for (int k = 0; k < 2; ++k)
#pragma unroll
        for (int r = 0; r < 3; ++r) { t3a[k][r] = 1.0f; t4a[k][r] = 1.0f; }

    for (int i0 = 0; i0 < 16; ++i0) {
        float4 xa = *(const float4*)&xj[j1 * XJST + i0 * 4];
        float4 xb = *(const float4*)&xj[j2e * XJST + i0 * 4];
        const float* xap = (const float*)&xa;
        const float* xbp = (const float*)&xb;
#pragma unroll
        for (int s = 0; s < 4; ++s) {
            const int i = i0 * 4 + s;
            const float2* k3 = (const float2*)&ck[((size_t)(i * 16 + c)) * 6];
            const float2* k4 = (const float2*)&ck[((size_t)((64 + i) * 16 + c)) * 6];
            float2 k30 = k3[0], k31 = k3[1], k32 = k3[2];
            float2 k40 = k4[0], k41 = k4[1], k42 = k4[2];
            float x1 = xap[s], x2 = xbp[s];
            t3a[0][0] *= fmaf(x1, k30.x, k30.y);
            t3a[0][1] *= fmaf(x1, k31.x, k31.y);
            t3a[0][2] *= fmaf(x1, k32.x, k32.y);
            t4a[0][0] *= fmaf(x1, k40.x, k40.y);
            t4a[0][1] *= fmaf(x1, k41.x, k41.y);
            t4a[0][2] *= fmaf(x1, k42.x, k42.y);
            t3a[1][0] *= fmaf(x2, k30.x, k30.y);
            t3a[1][1] *= fmaf(x2, k31.x, k31.y);
            t3a[1][2] *= fmaf(x2, k32.x, k32.y);
            t4a[1][0] *= fmaf(x2, k40.x, k40.y);
            t4a[1][1] *= fmaf(x2, k41.x, k41.y);
            t4a[1][2] *= fmaf(x2, k42.x, k42.y);
        }
    }

    {
        size_t base1 = ((size_t)ba * 23 + j1) * 48 + c;
#pragma unroll
        for (int r = 0; r < 3; ++r) {
            t3[base1 + r * 16] = t3a[0][r];
            t4[base1 + r * 16] = t4a[0][r];
        }
        if (j2 < 23) {
            size_t base2 = ((size_t)ba * 23 + j2) * 48 + c;
#pragma unroll
            for (int r = 0; r < 3; ++r) {
                t3[base2 + r * 16] = t3a[1][r];
                t4[base2 + r * 16] = t4a[1][r];
            }
        }
    }

    // ---- U1 (wave 0, lanes 0..47) and U2 (wave 1, lanes 64..111) ----
    if (tid < 48) {
        const int rc = tid, cr = rc & 15, r = rc >> 4;
        float acc = 1.0f;
#pragma unroll 8
        for (int i = 0; i < 32; ++i) {
            float2 de = dke_of(ak + (((size_t)(r * 16 + cr) * 288) + i) * 3, invT);
            acc *= fmaf(xn[i], de.x, de.y);
        }
#pragma unroll 8
        for (int i = 0; i < 64; ++i) {
            float2 de = dke_of(ak + (((size_t)(r * 16 + cr) * 288) + 32 + i) * 3, invT);
            acc *= fmaf(xu[i], de.x, de.y);
        }
        U1[(size_t)ba * 48 + rc] = acc;
    } else if (tid >= 64 && tid < 112) {
        const int rc = tid - 64, cr = rc & 15, r = rc >> 4;
        float acc = 1.0f;
#pragma unroll 8
        for (int i = 0; i < 64; ++i) {
            float2 de = dke_of(ak + (((size_t)(r * 16 + cr) * 288) + 96 + i) * 3, invT);
            acc *= fmaf(xu[i], de.x, de.y);
        }
        U2[(size_t)ba * 48 + rc] = acc;
    }
}

// ---------------- Kernel 2: combine + binary/unary reductions ----------------
// grid: 384 blocks (b,a). block: 64 threads = pl(4) x c(16); thread = 6 perms j=pl+4m.
__global__ __launch_bounds__(64) void combine2_kernel(const float* __restrict__ U1,
                                                      const float* __restrict__ U2,
                                                      const float* __restrict__ t3,
                                                      const float* __restrict__ t4,
                                                      const float* __restrict__ orK,
                                                      const float* __restrict__ temp,
                                                      float* __restrict__ out,
                                                      float* __restrict__ ws0) {
    __shared__ float u2sh[24 * 48];   // U2 for all bb of this b

    const int tid = threadIdx.x;
    const int b = blockIdx.x / 24;
    const int a = blockIdx.x % 24;
    const int pl = tid >> 4;
    const int c = tid & 15;

    for (int idx = tid; idx < 1152; idx += 64)
        u2sh[idx] = U2[(size_t)b * 1152 + idx];
    __syncthreads();

    float u1r[3];
#pragma unroll
    for (int r = 0; r < 3; ++r)
        u1r[r] = U1[(size_t)(b * 24 + a) * 48 + r * 16 + c];

    const float T = temp[0];
    const float ok2 = sigm(orK[32 + c] / T);
    float au1 = 1.0f, au0 = 1.0f;

#pragma unroll
    for (int m = 0; m < 6; ++m) {
        int j = pl + 4 * m;
        int jv = j < 23 ? j : 22;           // pad lane recomputes j=22, outputs masked
        int bb = jv + (jv >= a ? 1 : 0);
        int aadj = (a > bb) ? (a - 1) : a;
        size_t base3 = (((size_t)b * 24 + a) * 23 + jv) * 48 + c;
        size_t base4 = (((size_t)b * 24 + bb) * 23 + aadj) * 48 + c;
        float c0 = u1r[0] * u2sh[bb * 48 + c]      * t3[base3]      * t4[base4];
        float c1 = u1r[1] * u2sh[bb * 48 + 16 + c] * t3[base3 + 16] * t4[base4 + 16];
        float c2 = u1r[2] * u2sh[bb * 48 + 32 + c] * t3[base3 + 32] * t4[base4 + 32];
        float w = 1.0f - c2 * ok2;
#pragma unroll
        for (int off = 1; off < 16; off <<= 1) w *= __shfl_xor(w, off, 16);
        if (c == 0 && j < 23) out[400 + ((size_t)b * 24 + a) * 23 + j] = 1.0f - w;
        if (j < 23) {
            au1 *= (1.0f - c1);
            au0 *= (1.0f - c0);
        }
    }

    // fold across pl (tid bits 4,5)
    au1 *= __shfl_xor(au1, 16, 64);  au1 *= __shfl_xor(au1, 32, 64);
    au0 *= __shfl_xor(au0, 16, 64);  au0 *= __shfl_xor(au0, 32, 64);

    // unary out
    {
        float ok1 = sigm(orK[16 + c] / T);
        float w = 1.0f - (1.0f - au1) * ok1;
#pragma unroll
        for (int off = 1; off < 16; off <<= 1) w *= __shfl_xor(w, off, 16);
        if (tid == 0) out[16 + (size_t)b * 24 + a] = 1.0f - w;
    }
    // nullary partial
    if (pl == 0) ws0[((size_t)b * 24 + a) * 16 + c] = au0;
}

// ---------------- Kernel 3: nullary finish ----------------
__global__ __launch_bounds__(256) void final_kernel(const float* __restrict__ ws0,
                                                    const float* __restrict__ orK,
                                                    const float* __restrict__ temp,
                                                    float* __restrict__ out) {
    int tid = threadIdx.x;       // 256 = 16 b * 16 c
    int b = tid >> 4, c = tid & 15;
    float p = 1.0f;
#pragma unroll
    for (int a = 0; a < 24; ++a) p *= ws0[((size_t)b * 24 + a) * 16 + c];
    float T = temp[0];
    float ok0 = sigm(orK[c] / T);
    float w = 1.0f - (1.0f - p) * ok0;
#pragma unroll
    for (int off = 1; off < 16; off <<= 1) w *= __shfl_xor(w, off, 16);
    if (c == 0) out[b] = 1.0f - w;
}

extern "C" void kernel_launch(void* const* d_in, const int* in_sizes, int n_in,
                              void* d_out, int out_size, void* d_ws, size_t ws_size,
                              hipStream_t stream) {
    const float* nullary = (const float*)d_in[0];   // (16,32)
    const float* unary   = (const float*)d_in[1];   // (16,24,64)
    const float* binary  = (const float*)d_in[2];   // (16,24,23,64)
    const float* ak      = (const float*)d_in[3];   // (3,16,288,3)
    const float* orK     = (const float*)d_in[4];   // (3,16)
    const float* temp    = (const float*)d_in[5];   // scalar

    float* out = (float*)d_out;                     // 16 + 384 + 8832 floats
    float* t3  = (float*)d_ws;                      // 384*23*48 = 423936 floats
    float* t4  = t3 + 423936;                       // 423936
    float* U1  = t4 + 423936;                       // 18432
    float* U2  = U1 + 18432;                        // 18432
    float* ws0 = U2 + 18432;                        // 6144

    fused_kernel<<<16 * 24, 256, 0, stream>>>(nullary, unary, binary, ak, temp, t3, t4, U1, U2);
    combine2_kernel<<<384, 64, 0, stream>>>(U1, U2, t3, t4, orK, temp, out, ws0);
    final_kernel<<<1, 256, 0, stream>>>(ws0, orK, temp, out);
}